// Round 6
// baseline (153.867 us; speedup 1.0000x reference)
//
#include <hip/hip_runtime.h>
#include <stdint.h>

typedef unsigned short u16;
typedef __bf16 v8bf __attribute__((ext_vector_type(8)));
typedef float  v4f  __attribute__((ext_vector_type(4)));

#define NPIX   32768
#define DIM    256
#define KCODE  1024
#define HW     1024

// workspace layout (bytes)
#define WS_EB    0                         // bf16 [KCODE][DIM]  = 512 KB
#define WS_NORM  524288                    // f32  [KCODE]       = 4 KB
#define WS_ACC   (WS_NORM + 4096)          // f32  [1]

// ---------------------------------------------------------------- kernel A
__global__ __launch_bounds__(256) void k_prep(const float* __restrict__ E,
                                              u16* __restrict__ Eb,
                                              float* __restrict__ norms,
                                              float* __restrict__ acc) {
  const int c = blockIdx.x, t = threadIdx.x;
  const float v = E[c * DIM + t];
  const __bf16 h = (__bf16)v;
  Eb[c * DIM + t] = __builtin_bit_cast(unsigned short, h);
  float s = v * v;
  #pragma unroll
  for (int m = 32; m; m >>= 1) s += __shfl_xor(s, m, 64);
  __shared__ float wsum[4];
  if ((t & 63) == 0) wsum[t >> 6] = s;
  __syncthreads();
  if (t == 0) {
    norms[c] = wsum[0] + wsum[1] + wsum[2] + wsum[3];
    if (c == 0) *acc = 0.f;
  }
}

// ---------------------------------------------------------------- fused VQ
#define CT 64            // codes per c-iter
#define CITERS (KCODE / CT)

__device__ __forceinline__ void gld_lds16(const void* src, void* dst_wave_base) {
  const unsigned int ldsoff =
      __builtin_amdgcn_readfirstlane((unsigned int)(uintptr_t)dst_wave_base);
  __builtin_amdgcn_global_load_lds(
      (const __attribute__((address_space(1))) void*)(uintptr_t)src,
      (__attribute__((address_space(3))) void*)(uintptr_t)ldsoff,
      16, 0, 0);
}

// stage 64x256 bf16 E tile (32KB) into LDS, source pre-swizzled so the
// swizzled ds_read_b128 is bank-conflict-free (T2 both-sides-or-neither)
__device__ __forceinline__ void stage_tile(const u16* __restrict__ Eb, u16* tile,
                                           int c0, int t) {
  const int wv = t >> 6;
  #pragma unroll
  for (int r = 0; r < 8; ++r) {
    const int s  = r * 256 + t;              // 16B slot 0..2047
    const int sp = s ^ ((s >> 5) & 7);       // inverse swizzle on the source
    const char* src = (const char*)(Eb + (size_t)(c0 + (s >> 5)) * DIM)
                      + ((sp & 31) << 4);
    char* dst = (char*)tile + ((r * 256 + wv * 64) << 4);
    gld_lds16(src, dst);
  }
}

// smem regions (byte offsets), phase-disjoint aliasing:
//  [0,65536)      phase1: etile[2][64*256] u16   | phase0: tileA[2][32][132] f32 (33.8KB)
//                 phase2: er[256][65] f32 (66560B, also overlaps nlds start)
//  [65536,69632)  nlds[1024] f32   (phase1 only)
//  [69632,70144)  il[128] int      (phase1 write -> phase2 read)
//  [70144,70160)  wred[4] f32
#define SMEM_BYTES 70160

__global__ __launch_bounds__(256) void k_vq(const float* __restrict__ latents,
                                            const u16* __restrict__ Eb,
                                            const float* __restrict__ E,
                                            const float* __restrict__ norms,
                                            float* __restrict__ out,
                                            float* __restrict__ acc) {
  __shared__ __attribute__((aligned(16))) char smem[SMEM_BYTES];
  u16*   etile0 = (u16*)smem;
  u16*   etile1 = (u16*)(smem + 32768);
  float* tileA  = (float*)smem;                // [2][32][132]
  float* er     = (float*)smem;                // [256][65]
  float* nlds   = (float*)(smem + 65536);
  int*   il     = (int*)(smem + 69632);
  float* wred   = (float*)(smem + 70144);

  const int t    = threadIdx.x;
  const int lane = t & 63;
  const int wv   = t >> 6;               // 0..3
  const int l15  = lane & 15;
  const int l4   = lane >> 4;            // 0..3
  const int bid  = blockIdx.x;
  const int b    = bid >> 3;
  const int hw0  = (bid & 7) << 7;       // 128-pixel chunk

  #pragma unroll
  for (int r = 0; r < 4; ++r) nlds[t + r * 256] = norms[t + r * 256];

  // ---------------- phase 0: latents [D][hw] slab -> bf16 A-fragments ----
  const float* lp = latents + (((size_t)b * DIM) << 10) + hw0;
  float4 rg[2][4];
  #pragma unroll
  for (int i = 0; i < 4; ++i) {
    const int s = i * 256 + t;
    rg[0][i] = *(const float4*)(lp + (((size_t)(s >> 5)) << 10) + (s & 31) * 4);
  }
  v8bf a[2][8];
  #pragma unroll
  for (int kk = 0; kk < 8; ++kk) {
    float* tb = tileA + (kk & 1) * (32 * 132);
    if (kk < 7) {
      #pragma unroll
      for (int i = 0; i < 4; ++i) {
        const int s = i * 256 + t;
        rg[(kk + 1) & 1][i] =
            *(const float4*)(lp + (((size_t)((kk + 1) * 32 + (s >> 5))) << 10)
                             + (s & 31) * 4);
      }
    }
    #pragma unroll
    for (int i = 0; i < 4; ++i) {
      const int s = i * 256 + t;
      *(float4*)(tb + (s >> 5) * 132 + (s & 31) * 4) = rg[kk & 1][i];
    }
    __syncthreads();
    #pragma unroll
    for (int rf = 0; rf < 2; ++rf) {
      const int pix = wv * 32 + rf * 16 + l15;
      v8bf v;
      #pragma unroll
      for (int j = 0; j < 8; ++j)
        v[j] = (__bf16)tb[(l4 * 8 + j) * 132 + pix];
      a[rf][kk] = v;
    }
    __syncthreads();   // reads done before next iter's writes / etile staging
  }

  // ---------------- phase 1: argmin over codebook ------------------------
  stage_tile(Eb, etile0, 0, t);

  float minv[2][4];
  int   mini[2][4];
  #pragma unroll
  for (int rf = 0; rf < 2; ++rf)
    #pragma unroll
    for (int i = 0; i < 4; ++i) { minv[rf][i] = 3.4e38f; mini[rf][i] = 0; }

  __syncthreads();   // drains vmcnt(0): tile 0 staged

  for (int ci = 0; ci < CITERS; ++ci) {
    const u16* buf = (ci & 1) ? etile1 : etile0;
    if (ci + 1 < CITERS)
      stage_tile(Eb, (ci & 1) ? etile0 : etile1, (ci + 1) * CT, t);
    const int c0 = ci * CT;
    #pragma unroll
    for (int cf = 0; cf < 4; ++cf) {
      const int cl    = cf * 16 + l15;
      const int abase = cl * 512 + l4 * 16;
      const int sw    = (cl & 7) << 4;
      v8bf bfr[8];
      #pragma unroll
      for (int kk = 0; kk < 8; ++kk)
        bfr[kk] = *(const v8bf*)((const char*)buf + ((abase + kk * 64) ^ sw));
      v4f acc0 = {0.f, 0.f, 0.f, 0.f}, acc1 = {0.f, 0.f, 0.f, 0.f};
      #pragma unroll
      for (int kk = 0; kk < 8; ++kk) {
        acc0 = __builtin_amdgcn_mfma_f32_16x16x32_bf16(a[0][kk], bfr[kk], acc0, 0, 0, 0);
        acc1 = __builtin_amdgcn_mfma_f32_16x16x32_bf16(a[1][kk], bfr[kk], acc1, 0, 0, 0);
      }
      const int   c   = c0 + cl;
      const float nrm = nlds[c];
      #pragma unroll
      for (int i = 0; i < 4; ++i) {
        const float d0 = nrm - 2.f * acc0[i];
        if (d0 < minv[0][i]) { minv[0][i] = d0; mini[0][i] = c; }
        const float d1 = nrm - 2.f * acc1[i];
        if (d1 < minv[1][i]) { minv[1][i] = d1; mini[1][i] = c; }
      }
    }
    __syncthreads();  // next tile staged + safe to overwrite read buffer
  }

  // per-row argmin: butterfly across the 16 lanes sharing a row
  #pragma unroll
  for (int rf = 0; rf < 2; ++rf)
    #pragma unroll
    for (int i = 0; i < 4; ++i) {
      float v  = minv[rf][i];
      int   ix = mini[rf][i];
      #pragma unroll
      for (int m = 1; m < 16; m <<= 1) {
        const float ov = __shfl_xor(v, m, 64);
        const int   oi = __shfl_xor(ix, m, 64);
        if (ov < v || (ov == v && oi < ix)) { v = ov; ix = oi; }
      }
      if (l15 == 0) il[wv * 32 + rf * 16 + l4 * 4 + i] = ix;
    }
  __syncthreads();   // il visible; etile/nlds dead -> er may be written

  // ---------------- phase 2: gather + transposed write + loss ------------
  float lsum = 0.f;
  #pragma unroll 1
  for (int s = 0; s < 2; ++s) {
    // stage 64 gathered E rows, d-major with XOR swizzle on the pixel col
    for (int q = 0; q < 16; ++q) {
      const int p   = wv + q * 4;
      const int idx = il[s * 64 + p];
      #pragma unroll
      for (int c = 0; c < 4; ++c) {
        const int d = lane + 64 * c;
        er[d * 65 + (p ^ ((d >> 4) & 3))] = E[(size_t)idx * DIM + d];
      }
    }
    __syncthreads();
    // loss: waves whose pixels live in this stage
    if ((wv >> 1) == s) {
      #pragma unroll
      for (int rf = 0; rf < 2; ++rf) {
        const int p = (wv & 1) * 32 + rf * 16 + l15;
        #pragma unroll
        for (int kk = 0; kk < 8; ++kk) {
          #pragma unroll
          for (int j = 0; j < 8; ++j) {
            const int d  = kk * 32 + l4 * 8 + j;
            const float qv = er[d * 65 + (p ^ ((d >> 4) & 3))];
            const float xv = (float)a[rf][kk][j];
            const float df = qv - xv;
            lsum = fmaf(df, df, lsum);
          }
        }
      }
    }
    // transposed coalesced output write: wave wv owns d in [wv*64, wv*64+64)
    {
      const int dg  = l4;
      const int hw4 = l15;
      float* op = out + (((size_t)b * DIM) << 10) + hw0 + s * 64;
      #pragma unroll
      for (int r = 0; r < 16; ++r) {
        const int d = wv * 64 + dg * 16 + r;
        const int f = (d >> 4) & 3;   // == dg
        float4 v;
        v.x = er[d * 65 + ((4 * hw4 + 0) ^ f)];
        v.y = er[d * 65 + ((4 * hw4 + 1) ^ f)];
        v.z = er[d * 65 + ((4 * hw4 + 2) ^ f)];
        v.w = er[d * 65 + ((4 * hw4 + 3) ^ f)];
        *(float4*)(op + (((size_t)d) << 10) + 4 * hw4) = v;
      }
    }
    __syncthreads();   // er reads done before next stage overwrites
  }

  // block loss reduction -> one atomic
  #pragma unroll
  for (int m = 32; m; m >>= 1) lsum += __shfl_xor(lsum, m, 64);
  if (lane == 0) wred[wv] = lsum;
  __syncthreads();
  if (t == 0) atomicAdd(acc, wred[0] + wred[1] + wred[2] + wred[3]);
}

// ---------------------------------------------------------------- kernel D
__global__ void k_final(const float* __restrict__ acc, float* __restrict__ loss) {
  // vq_loss = (BETA + 1) * mean = 1.25 * sum / (N*D)
  *loss = *acc * (1.25f / 8388608.f);
}

// ----------------------------------------------------------------
extern "C" void kernel_launch(void* const* d_in, const int* in_sizes, int n_in,
                              void* d_out, int out_size, void* d_ws, size_t ws_size,
                              hipStream_t stream) {
  const float* latents = (const float*)d_in[0];
  const float* E       = (const float*)d_in[1];
  float* out = (float*)d_out;
  char*  ws  = (char*)d_ws;
  u16*   Eb    = (u16*)(ws + WS_EB);
  float* norms = (float*)(ws + WS_NORM);
  float* acc   = (float*)(ws + WS_ACC);

  k_prep<<<KCODE, 256, 0, stream>>>(E, Eb, norms, acc);
  k_vq<<<256, 256, 0, stream>>>(latents, Eb, E, norms, out, acc);
  k_final<<<1, 1, 0, stream>>>(acc, out + 8388608);
}

// Round 8
// 125.784 us; speedup vs baseline: 1.2233x; 1.2233x over previous
//
#include <hip/hip_runtime.h>
#include <stdint.h>

typedef unsigned short u16;
typedef __bf16 v8bf __attribute__((ext_vector_type(8)));
typedef float  v4f  __attribute__((ext_vector_type(4)));

#define NPIX   32768
#define DIM    256
#define KCODE  1024
#define HW     1024

// workspace layout (bytes)
#define WS_EB    0                         // bf16 [KCODE][DIM]  = 512 KB
#define WS_NORM  524288                    // f32  [KCODE]       = 4 KB
#define WS_ACC   (WS_NORM + 4096)          // f32  [1]

// ---------------------------------------------------------------- kernel A
__global__ __launch_bounds__(256) void k_prep(const float* __restrict__ E,
                                              u16* __restrict__ Eb,
                                              float* __restrict__ norms,
                                              float* __restrict__ acc) {
  const int c = blockIdx.x, t = threadIdx.x;
  const float v = E[c * DIM + t];
  const __bf16 h = (__bf16)v;
  Eb[c * DIM + t] = __builtin_bit_cast(unsigned short, h);
  float s = v * v;
  #pragma unroll
  for (int m = 32; m; m >>= 1) s += __shfl_xor(s, m, 64);
  __shared__ float wsum[4];
  if ((t & 63) == 0) wsum[t >> 6] = s;
  __syncthreads();
  if (t == 0) {
    norms[c] = wsum[0] + wsum[1] + wsum[2] + wsum[3];
    if (c == 0) *acc = 0.f;
  }
}

// ---------------------------------------------------------------- fused VQ
// NT=64 pixels/block, grid 512 -> 2 blocks/CU (8 waves/CU) for latency hiding.
#define NT 64
#define CT 64            // codes per c-iter
#define CITERS (KCODE / CT)

__device__ __forceinline__ void gld_lds16(const void* src, void* dst_wave_base) {
  const unsigned int ldsoff =
      __builtin_amdgcn_readfirstlane((unsigned int)(uintptr_t)dst_wave_base);
  __builtin_amdgcn_global_load_lds(
      (const __attribute__((address_space(1))) void*)(uintptr_t)src,
      (__attribute__((address_space(3))) void*)(uintptr_t)ldsoff,
      16, 0, 0);
}

// stage 64x256 bf16 E tile (32KB) into LDS, source pre-swizzled so the
// swizzled ds_read_b128 is bank-conflict-free (T2 both-sides-or-neither)
__device__ __forceinline__ void stage_tile(const u16* __restrict__ Eb, u16* tile,
                                           int c0, int t) {
  const int wv = t >> 6;
  #pragma unroll
  for (int r = 0; r < 8; ++r) {
    const int s  = r * 256 + t;              // 16B slot 0..2047
    const int sp = s ^ ((s >> 5) & 7);       // inverse swizzle on the source
    const char* src = (const char*)(Eb + (size_t)(c0 + (s >> 5)) * DIM)
                      + ((sp & 31) << 4);
    char* dst = (char*)tile + ((r * 256 + wv * 64) << 4);
    gld_lds16(src, dst);
  }
}

// smem regions (byte offsets), phase-disjoint aliasing:
//  [0,65536)      phase1: etile[2][64*256] u16 | phase0: tileA[2][32][68] f32 (17.4KB)
//                 phase2: er[256][65] f32 (66552B, overlaps nlds start - nlds dead)
//  [65536,69632)  nlds[1024] f32   (phase1 only)
//  [69632,70144)  il[64] int       (phase1 write -> phase2 read)
//  [70144,70160)  wred[4] f32
#define SMEM_BYTES 70160

__global__ __launch_bounds__(256) void k_vq(const float* __restrict__ latents,
                                            const u16* __restrict__ Eb,
                                            const float* __restrict__ E,
                                            const float* __restrict__ norms,
                                            float* __restrict__ out,
                                            float* __restrict__ acc) {
  __shared__ __attribute__((aligned(16))) char smem[SMEM_BYTES];
  u16*   etile0 = (u16*)smem;
  u16*   etile1 = (u16*)(smem + 32768);
  float* tileA  = (float*)smem;                // [2][32][68]
  float* er     = (float*)smem;                // [256][65]
  float* nlds   = (float*)(smem + 65536);
  int*   il     = (int*)(smem + 69632);
  float* wred   = (float*)(smem + 70144);

  const int t    = threadIdx.x;
  const int lane = t & 63;
  const int wv   = t >> 6;               // 0..3
  const int l15  = lane & 15;
  const int l4   = lane >> 4;            // 0..3
  const int bid  = blockIdx.x;
  const int b    = bid >> 4;
  const int hw0  = (bid & 15) << 6;      // 64-pixel chunk

  #pragma unroll
  for (int r = 0; r < 4; ++r) nlds[t + r * 256] = norms[t + r * 256];

  // ---------------- phase 0: latents [D][hw] slab -> bf16 A-fragments ----
  // per kk: 32 d x 64 hw f32 (8KB), double-buffered tile [32][68]
  const float* lp = latents + (((size_t)b * DIM) << 10) + hw0;
  float4 rg[2][2];
  #pragma unroll
  for (int i = 0; i < 2; ++i) {
    const int s = i * 256 + t;           // float4 slot: d = s>>4, hw = 4*(s&15)
    rg[0][i] = *(const float4*)(lp + (((size_t)(s >> 4)) << 10) + (s & 15) * 4);
  }
  v8bf a[8];
  #pragma unroll
  for (int kk = 0; kk < 8; ++kk) {
    float* tb = tileA + (kk & 1) * (32 * 68);
    if (kk < 7) {
      #pragma unroll
      for (int i = 0; i < 2; ++i) {
        const int s = i * 256 + t;
        rg[(kk + 1) & 1][i] =
            *(const float4*)(lp + (((size_t)((kk + 1) * 32 + (s >> 4))) << 10)
                             + (s & 15) * 4);
      }
    }
    #pragma unroll
    for (int i = 0; i < 2; ++i) {
      const int s = i * 256 + t;
      *(float4*)(tb + (s >> 4) * 68 + (s & 15) * 4) = rg[kk & 1][i];
    }
    __syncthreads();
    {
      const int pix = wv * 16 + l15;
      v8bf v;
      #pragma unroll
      for (int j = 0; j < 8; ++j)
        v[j] = (__bf16)tb[(l4 * 8 + j) * 68 + pix];
      a[kk] = v;
    }
    __syncthreads();   // reads done before next iter's writes / etile staging
  }

  // ---------------- phase 1: argmin over codebook ------------------------
  stage_tile(Eb, etile0, 0, t);

  float minv[4];
  int   mini[4];
  #pragma unroll
  for (int i = 0; i < 4; ++i) { minv[i] = 3.4e38f; mini[i] = 0; }

  __syncthreads();   // drains vmcnt(0): tile 0 staged

  for (int ci = 0; ci < CITERS; ++ci) {
    const u16* buf = (ci & 1) ? etile1 : etile0;
    if (ci + 1 < CITERS)
      stage_tile(Eb, (ci & 1) ? etile0 : etile1, (ci + 1) * CT, t);
    const int c0 = ci * CT;
    #pragma unroll
    for (int cf = 0; cf < 4; ++cf) {
      const int cl    = cf * 16 + l15;
      const int abase = cl * 512 + l4 * 16;
      const int sw    = (cl & 7) << 4;
      v8bf bfr[8];
      #pragma unroll
      for (int kk = 0; kk < 8; ++kk)
        bfr[kk] = *(const v8bf*)((const char*)buf + ((abase + kk * 64) ^ sw));
      v4f acc0 = {0.f, 0.f, 0.f, 0.f};
      #pragma unroll
      for (int kk = 0; kk < 8; ++kk)
        acc0 = __builtin_amdgcn_mfma_f32_16x16x32_bf16(a[kk], bfr[kk], acc0, 0, 0, 0);
      const int   c   = c0 + cl;
      const float nrm = nlds[c];
      #pragma unroll
      for (int i = 0; i < 4; ++i) {
        const float d0 = nrm - 2.f * acc0[i];
        if (d0 < minv[i]) { minv[i] = d0; mini[i] = c; }
      }
    }
    __syncthreads();  // next tile staged + safe to overwrite read buffer
  }

  // per-row argmin: butterfly across the 16 lanes sharing a row
  #pragma unroll
  for (int i = 0; i < 4; ++i) {
    float v  = minv[i];
    int   ix = mini[i];
    #pragma unroll
    for (int m = 1; m < 16; m <<= 1) {
      const float ov = __shfl_xor(v, m, 64);
      const int   oi = __shfl_xor(ix, m, 64);
      if (ov < v || (ov == v && oi < ix)) { v = ov; ix = oi; }
    }
    if (l15 == 0) il[wv * 16 + l4 * 4 + i] = ix;
  }
  __syncthreads();   // il visible; etile/nlds dead -> er may be written

  // ---------------- phase 2: gather + transposed write + loss ------------
  float lsum = 0.f;
  // stage 64 gathered E rows, d-major with XOR swizzle on the pixel col
  for (int q = 0; q < 16; ++q) {
    const int p   = wv + q * 4;
    const int idx = il[p];
    #pragma unroll
    for (int c = 0; c < 4; ++c) {
      const int d = lane + 64 * c;
      er[d * 65 + (p ^ ((d >> 4) & 3))] = E[(size_t)idx * DIM + d];
    }
  }
  __syncthreads();
  // loss: each wave owns its 16 pixels (matches A-fragment ownership)
  {
    const int p = wv * 16 + l15;
    #pragma unroll
    for (int kk = 0; kk < 8; ++kk) {
      #pragma unroll
      for (int j = 0; j < 8; ++j) {
        const int d  = kk * 32 + l4 * 8 + j;
        const float qv = er[d * 65 + (p ^ ((d >> 4) & 3))];
        const float xv = (float)a[kk][j];
        const float df = qv - xv;
        lsum = fmaf(df, df, lsum);
      }
    }
  }
  // transposed coalesced output write: wave wv owns d in [wv*64, wv*64+64)
  {
    const int dg  = l4;
    const int hw4 = l15;
    float* op = out + (((size_t)b * DIM) << 10) + hw0;
    #pragma unroll
    for (int r = 0; r < 16; ++r) {
      const int d = wv * 64 + dg * 16 + r;
      const int f = (d >> 4) & 3;   // == dg
      float4 v;
      v.x = er[d * 65 + ((4 * hw4 + 0) ^ f)];
      v.y = er[d * 65 + ((4 * hw4 + 1) ^ f)];
      v.z = er[d * 65 + ((4 * hw4 + 2) ^ f)];
      v.w = er[d * 65 + ((4 * hw4 + 3) ^ f)];
      *(float4*)(op + (((size_t)d) << 10) + 4 * hw4) = v;
    }
  }

  // block loss reduction -> one atomic
  #pragma unroll
  for (int m = 32; m; m >>= 1) lsum += __shfl_xor(lsum, m, 64);
  if (lane == 0) wred[wv] = lsum;
  __syncthreads();
  if (t == 0) atomicAdd(acc, wred[0] + wred[1] + wred[2] + wred[3]);
}

// ---------------------------------------------------------------- kernel D
__global__ void k_final(const float* __restrict__ acc, float* __restrict__ loss) {
  // vq_loss = (BETA + 1) * mean = 1.25 * sum / (N*D)
  *loss = *acc * (1.25f / 8388608.f);
}

// ----------------------------------------------------------------
extern "C" void kernel_launch(void* const* d_in, const int* in_sizes, int n_in,
                              void* d_out, int out_size, void* d_ws, size_t ws_size,
                              hipStream_t stream) {
  const float* latents = (const float*)d_in[0];
  const float* E       = (const float*)d_in[1];
  float* out = (float*)d_out;
  char*  ws  = (char*)d_ws;
  u16*   Eb    = (u16*)(ws + WS_EB);
  float* norms = (float*)(ws + WS_NORM);
  float* acc   = (float*)(ws + WS_ACC);

  k_prep<<<KCODE, 256, 0, stream>>>(E, Eb, norms, acc);
  k_vq<<<NPIX / NT, 256, 0, stream>>>(latents, Eb, E, norms, out, acc);
  k_final<<<1, 1, 0, stream>>>(acc, out + 8388608);
}